// Round 3
// baseline (418.837 us; speedup 1.0000x reference)
//
#include <hip/hip_runtime.h>
#include <hip/hip_bf16.h>
#include <stdint.h>

// Problem constants
#define BSZ 256
#define NQ 4096          // Q_SIZE
#define N1 8320          // GEMM1 padded N: [qkv_half 4096 | gate 4096 | alpha 32 | beta 32 | pad 64]
#define K1 2048
#define N3 2048
#define K3 4096
#define Z3 4             // gemm3 split-K slabs

typedef __attribute__((ext_vector_type(8))) short bf16x8;
typedef __attribute__((ext_vector_type(4))) float f32x4;

__device__ __forceinline__ unsigned short f2bf(float f) {
  union { float f; unsigned u; } v; v.f = f;
  unsigned r = v.u + 0x7fffu + ((v.u >> 16) & 1u);   // RNE
  return (unsigned short)(r >> 16);
}

// fp32x8 -> bf16x8 via v_cvt_pk_bf16_f32 (RNE, same numerics as f2bf)
__device__ __forceinline__ bf16x8 pack8(float4 a, float4 b) {
  union { bf16x8 v; __hip_bfloat162 h[4]; } o;
  o.h[0] = __float22bfloat162_rn(float2{a.x, a.y});
  o.h[1] = __float22bfloat162_rn(float2{a.z, a.w});
  o.h[2] = __float22bfloat162_rn(float2{b.x, b.y});
  o.h[3] = __float22bfloat162_rn(float2{b.z, b.w});
  return o.v;
}

// ---------------- K0: hidden fp32 -> bf16 ----------------
__global__ __launch_bounds__(256) void cvt_kernel(const float* __restrict__ x,
                                                  unsigned short* __restrict__ y) {
  int i = (blockIdx.x * 256 + threadIdx.x) * 8;
  float4 a = *(const float4*)(x + i);
  float4 b = *(const float4*)(x + i + 4);
  ushort4 o0 = { f2bf(a.x), f2bf(a.y), f2bf(a.z), f2bf(a.w) };
  ushort4 o1 = { f2bf(b.x), f2bf(b.y), f2bf(b.z), f2bf(b.w) };
  *(ushort4*)(y + i) = o0;
  *(ushort4*)(y + i + 4) = o1;
}

// ================= GEMM core: wave-autonomous, no LDS, no barriers =================
// Each wave owns an M16 x N32 output tile, streaming B (fp32 weights) directly
// from HBM into registers and A (bf16) from L1/L2. MFMA 16x16x32 fragment
// mapping (verified against the previous LDS-path kernel byte-for-byte):
//   A-frag lane l: A[m0 + (l&15)][kk + 8*(l>>4) .. +8]   (16 B load)
//   B-frag lane l: B[n  + (l&15)][kk + 8*(l>>4) .. +8]   (2x16 B fp32 loads)
// One global_load_dwordx4 covers 16 rows x 64 B contiguous -> DRAM-friendly.
// No __syncthreads anywhere: waves free-run; compiler pipelines ~20 loads in
// flight per wave (unroll 4). Blocks' 4 waves share the M-strip for L1 reuse.

// ---------------- K1: GEMM1  P = hidden @ [Wqkv_half;Wgate;Walpha;Wbeta]^T ----------------
// waves: 16 strips x 260 n-groups = 4160; grid 1040 x 256thr
__global__ __launch_bounds__(256) void gemm1_kernel(
    const unsigned short* __restrict__ A16,   // [256][2048] bf16
    const float* __restrict__ Wqkv, const float* __restrict__ Wgate,
    const float* __restrict__ Walpha, const float* __restrict__ Wbeta,
    float* __restrict__ P) {                  // [256][8320] fp32
  const int tid = threadIdx.x, lane = tid & 63, wv = tid >> 6;
  const int l15 = lane & 15, hi8 = (lane >> 4) * 8;
  const int wid = blockIdx.x * 4 + wv;        // 0..4159
  const int nidx = wid % 260;                 // 65 blocks per strip (260 % 4 == 0)
  const int strip = wid / 260;                // 0..15
  const int m0 = strip * 16;
  const int n0 = nidx * 32;

  const unsigned short* Arow = A16 + (size_t)(m0 + l15) * K1 + hi8;
  const float* Brow0;
  const float* Brow1;
  {
    int ng0 = n0 + l15;
    int ng1 = n0 + 16 + l15;
    const float* b0;
    const float* b1;
    if (ng0 < 4096)       b0 = Wqkv  + (size_t)(4096 + ng0) * K1;
    else if (ng0 < 8192)  b0 = Wgate + (size_t)(ng0 - 4096) * K1;
    else if (ng0 < 8224)  b0 = Walpha + (size_t)(ng0 - 8192) * K1;
    else if (ng0 < 8256)  b0 = Wbeta + (size_t)(ng0 - 8224) * K1;
    else                  b0 = Walpha + (size_t)l15 * K1;          // pad, never read back
    if (ng1 < 4096)       b1 = Wqkv  + (size_t)(4096 + ng1) * K1;
    else if (ng1 < 8192)  b1 = Wgate + (size_t)(ng1 - 4096) * K1;
    else if (ng1 < 8224)  b1 = Walpha + (size_t)(ng1 - 8192) * K1;
    else if (ng1 < 8256)  b1 = Wbeta + (size_t)(ng1 - 8224) * K1;
    else                  b1 = Walpha + (size_t)l15 * K1;          // pad
    Brow0 = b0 + hi8;
    Brow1 = b1 + hi8;
  }

  f32x4 acc0 = {0.f, 0.f, 0.f, 0.f};
  f32x4 acc1 = {0.f, 0.f, 0.f, 0.f};
#pragma unroll 4
  for (int kk = 0; kk < K1; kk += 32) {
    bf16x8 aF = *(const bf16x8*)(Arow + kk);
    float4 b0a = *(const float4*)(Brow0 + kk);
    float4 b0b = *(const float4*)(Brow0 + kk + 4);
    float4 b1a = *(const float4*)(Brow1 + kk);
    float4 b1b = *(const float4*)(Brow1 + kk + 4);
    acc0 = __builtin_amdgcn_mfma_f32_16x16x32_bf16(aF, pack8(b0a, b0b), acc0, 0, 0, 0);
    acc1 = __builtin_amdgcn_mfma_f32_16x16x32_bf16(aF, pack8(b1a, b1b), acc1, 0, 0, 0);
  }

  const int row = m0 + (lane >> 4) * 4;
#pragma unroll
  for (int r = 0; r < 4; r++) {
    P[(size_t)(row + r) * N1 + (n0 + l15)] = acc0[r];
    P[(size_t)(row + r) * N1 + (n0 + 16 + l15)] = acc1[r];
  }
}

// ---------------- K2: per-row fused conv + SSM + RMS + gate; writes core bf16 ----------------
__global__ __launch_bounds__(512) void fuse_kernel(
    const float* __restrict__ P,        // [256][8320]
    const float* __restrict__ bqkv,     // [8192]
    const float* __restrict__ ck,       // [8192][4]
    const float* __restrict__ cstate,   // [256][4][8192]
    const float* __restrict__ ssa,      // [32]
    const float* __restrict__ dtb,      // [32]
    const float* __restrict__ nw,       // [128]
    const float* __restrict__ sstate,   // [256][32]
    unsigned short* __restrict__ C16) { // [256][4096] bf16
  __shared__ __align__(16) float cb[4096];
  __shared__ float gsum[64];
  __shared__ float ssl[32];
  __shared__ float red[16];
  const int b = blockIdx.x, tid = threadIdx.x;
  const int lane = tid & 63, wv = tid >> 6;
  const float* P0 = P + (size_t)b * N1;

  if (wv == 0) {   // mean(ssm_norm_weight)
    float m = nw[lane] + nw[lane + 64];
#pragma unroll
    for (int off = 32; off; off >>= 1) m += __shfl_down(m, off, 64);
    if (lane == 0) red[8] = m * (1.f / 128.f);
  }

  // pass 1: core_base (conv) + group sums via 16-lane shuffle reduce
#pragma unroll
  for (int it = 0; it < 2; it++) {
    int j = (it * 512 + tid) * 4;
    float4 q0 = *(const float4*)(P0 + j);
    float4 bq = *(const float4*)(bqkv + NQ + j);
    float mqx = q0.x + bq.x, mqy = q0.y + bq.y;
    float mqz = q0.z + bq.z, mqw = q0.w + bq.w;
    const float* csb = cstate + (size_t)b * 4 * 8192 + NQ + j;
    float4 c1 = *(const float4*)(csb + 8192);
    float4 c2 = *(const float4*)(csb + 16384);
    float4 c3 = *(const float4*)(csb + 24576);
    float4 k0v = *(const float4*)(ck + (size_t)(NQ + j) * 4);
    float4 k1v = *(const float4*)(ck + (size_t)(NQ + j + 1) * 4);
    float4 k2v = *(const float4*)(ck + (size_t)(NQ + j + 2) * 4);
    float4 k3v = *(const float4*)(ck + (size_t)(NQ + j + 3) * 4);
    float4 cbv;
    cbv.x = c1.x * k0v.x + c2.x * k0v.y + c3.x * k0v.z + mqx * k0v.w;
    cbv.y = c1.y * k1v.x + c2.y * k1v.y + c3.y * k1v.z + mqy * k1v.w;
    cbv.z = c1.z * k2v.x + c2.z * k2v.y + c3.z * k2v.z + mqz * k2v.w;
    cbv.w = c1.w * k3v.x + c2.w * k3v.y + c3.w * k3v.z + mqw * k3v.w;
    *(float4*)(cb + j) = cbv;
    float s = cbv.x + cbv.y + cbv.z + cbv.w;
    s += __shfl_xor(s, 1, 64); s += __shfl_xor(s, 2, 64);
    s += __shfl_xor(s, 4, 64); s += __shfl_xor(s, 8, 64);
    if ((lane & 15) == 0) gsum[(it * 512 + tid) >> 4] = s;
  }
  __syncthreads();

  if (tid < 32) {
    float a  = P0[8192 + tid];
    float bc = P0[8224 + tid];
    float kg = gsum[tid] * (1.f / 64.f);
    float vg = gsum[32 + tid] * (1.f / 64.f);
    float x = a + dtb[tid];
    float sp = fmaxf(x, 0.f) + log1pf(expf(-fabsf(x)));   // stable softplus
    float g = -expf(ssa[tid]) * sp;
    float beta = 1.f / (1.f + expf(-bc));
    float ns = expf(g) * sstate[b * 32 + tid] + beta * vg;
    ssl[tid] = ns / (1.f + expf(-kg));
  }
  __syncthreads();

  // pass 2: core1 = core_base + expanded; sum of squares
  float sq = 0.f;
  float4 c1r[2];
#pragma unroll
  for (int it = 0; it < 2; it++) {
    int j = (it * 512 + tid) * 4;
    float4 v = *(const float4*)(cb + j);
    float sv = ssl[j >> 7];
    v.x += sv; v.y += sv; v.z += sv; v.w += sv;
    c1r[it] = v;
    sq += v.x * v.x + v.y * v.y + v.z * v.z + v.w * v.w;
  }
#pragma unroll
  for (int off = 32; off; off >>= 1) sq += __shfl_down(sq, off, 64);
  if (lane == 0) red[wv] = sq;
  __syncthreads();
  if (tid == 0) {
    float t = red[0] + red[1] + red[2] + red[3] + red[4] + red[5] + red[6] + red[7];
    red[9] = rsqrtf(t * (1.f / 4096.f) + 1e-6f);
  }
  __syncthreads();
  float rms = red[9], mwv = red[8];

  // pass 3: apply gate, write bf16
#pragma unroll
  for (int it = 0; it < 2; it++) {
    int j = (it * 512 + tid) * 4;
    float4 g0x = *(const float4*)(P0 + NQ + j);
    float4 v = c1r[it];
    float ox = v.x * rms * mwv / (1.f + expf(-g0x.x));
    float oy = v.y * rms * mwv / (1.f + expf(-g0x.y));
    float oz = v.z * rms * mwv / (1.f + expf(-g0x.z));
    float ow = v.w * rms * mwv / (1.f + expf(-g0x.w));
    ushort4 u = { f2bf(ox), f2bf(oy), f2bf(oz), f2bf(ow) };
    *(ushort4*)(C16 + (size_t)b * 4096 + j) = u;
  }
}

// ---------------- K3: GEMM3 OP[z] = core @ Wout^T (split-K=4, wave-autonomous) ----------------
// per z: 16 strips x 64 n-groups = 1024 waves; grid (256, 4) x 256thr
__global__ __launch_bounds__(256) void gemm3_kernel(
    const unsigned short* __restrict__ A16,  // core [256][4096] bf16
    const float* __restrict__ Wout,          // [2048][4096] fp32
    float* __restrict__ OP) {                // [4][256][2048] fp32 slabs
  const int tid = threadIdx.x, lane = tid & 63, wv = tid >> 6;
  const int l15 = lane & 15, hi8 = (lane >> 4) * 8;
  const int wid = blockIdx.x * 4 + wv;        // 0..1023
  const int z = blockIdx.y;                   // 0..3
  const int nidx = wid % 64;                  // 16 blocks per strip (64 % 4 == 0)
  const int strip = wid / 64;                 // 0..15
  const int m0 = strip * 16;
  const int n0 = nidx * 32;
  const int kb = z * 1024;

  const unsigned short* Arow = A16 + (size_t)(m0 + l15) * K3 + kb + hi8;
  const float* Brow0 = Wout + (size_t)(n0 + l15) * K3 + kb + hi8;
  const float* Brow1 = Wout + (size_t)(n0 + 16 + l15) * K3 + kb + hi8;

  f32x4 acc0 = {0.f, 0.f, 0.f, 0.f};
  f32x4 acc1 = {0.f, 0.f, 0.f, 0.f};
#pragma unroll 4
  for (int kk = 0; kk < 1024; kk += 32) {
    bf16x8 aF = *(const bf16x8*)(Arow + kk);
    float4 b0a = *(const float4*)(Brow0 + kk);
    float4 b0b = *(const float4*)(Brow0 + kk + 4);
    float4 b1a = *(const float4*)(Brow1 + kk);
    float4 b1b = *(const float4*)(Brow1 + kk + 4);
    acc0 = __builtin_amdgcn_mfma_f32_16x16x32_bf16(aF, pack8(b0a, b0b), acc0, 0, 0, 0);
    acc1 = __builtin_amdgcn_mfma_f32_16x16x32_bf16(aF, pack8(b1a, b1b), acc1, 0, 0, 0);
  }

  float* Oz = OP + (size_t)z * ((size_t)BSZ * N3);
  const int row = m0 + (lane >> 4) * 4;
#pragma unroll
  for (int r = 0; r < 4; r++) {
    Oz[(size_t)(row + r) * N3 + (n0 + l15)] = acc0[r];
    Oz[(size_t)(row + r) * N3 + (n0 + 16 + l15)] = acc1[r];
  }
}

// ---------------- K4: reduce 4 slabs -> out ----------------
__global__ __launch_bounds__(256) void reduce_kernel(const float* __restrict__ OP,
                                                     float* __restrict__ out) {
  int i = (blockIdx.x * 256 + threadIdx.x) * 4;
  float4 s = *(const float4*)(OP + i);
#pragma unroll
  for (int z = 1; z < Z3; z++) {
    float4 v = *(const float4*)(OP + (size_t)z * BSZ * N3 + i);
    s.x += v.x; s.y += v.y; s.z += v.z; s.w += v.w;
  }
  *(float4*)(out + i) = s;
}

extern "C" void kernel_launch(void* const* d_in, const int* in_sizes, int n_in,
                              void* d_out, int out_size, void* d_ws, size_t ws_size,
                              hipStream_t stream) {
  const float* hidden = (const float*)d_in[0];
  const float* Wqkv   = (const float*)d_in[1];
  const float* bqkv   = (const float*)d_in[2];
  const float* Wgate  = (const float*)d_in[3];
  const float* Walpha = (const float*)d_in[4];
  const float* Wbeta  = (const float*)d_in[5];
  const float* Wout   = (const float*)d_in[6];
  const float* ssa    = (const float*)d_in[7];
  const float* dtb    = (const float*)d_in[8];
  const float* nw     = (const float*)d_in[9];
  const float* ck     = (const float*)d_in[10];
  const float* sstate = (const float*)d_in[11];
  const float* cstate = (const float*)d_in[12];
  float* out = (float*)d_out;

  char* ws = (char*)d_ws;
  unsigned short* A16 = (unsigned short*)ws;                          // 1 MB
  float* P   = (float*)(ws + (1 << 20));                              // 256*8320*4 = 8,519,680 B
  unsigned short* C16 = (unsigned short*)(ws + (1 << 20) + 8519680);  // 2 MB
  float* OP  = (float*)(ws + (1 << 20) + 8519680 + (2 << 20));        // 4*256*2048*4 = 8 MB

  cvt_kernel<<<256, 256, 0, stream>>>(hidden, A16);
  gemm1_kernel<<<1040, 256, 0, stream>>>(A16, Wqkv, Wgate, Walpha, Wbeta, P);
  fuse_kernel<<<256, 512, 0, stream>>>(P, bqkv, ck, cstate, ssa, dtb, nw, sstate, C16);
  gemm3_kernel<<<dim3(256, 4), 256, 0, stream>>>(C16, Wout, OP);
  reduce_kernel<<<512, 256, 0, stream>>>(OP, out);
}

// Round 4
// 356.025 us; speedup vs baseline: 1.1764x; 1.1764x over previous
//
#include <hip/hip_runtime.h>
#include <hip/hip_bf16.h>
#include <stdint.h>

// Problem constants
#define BSZ 256
#define NQ 4096          // Q_SIZE
#define N1 8320          // GEMM1 padded N: [qkv_half 4096 | gate 4096 | alpha 32 | beta 32 | pad 64]
#define K1 2048
#define N3 2048
#define K3 4096
#define Z3 4             // gemm3 split-K slabs

typedef __attribute__((ext_vector_type(8))) short bf16x8;
typedef __attribute__((ext_vector_type(4))) float f32x4;

__device__ __forceinline__ unsigned short f2bf(float f) {
  union { float f; unsigned u; } v; v.f = f;
  unsigned r = v.u + 0x7fffu + ((v.u >> 16) & 1u);   // RNE
  return (unsigned short)(r >> 16);
}

// fp32x8 -> bf16x8 via v_cvt_pk_bf16_f32 (RNE, same numerics as f2bf)
__device__ __forceinline__ bf16x8 pack8(float4 a, float4 b) {
  union { bf16x8 v; __hip_bfloat162 h[4]; } o;
  o.h[0] = __float22bfloat162_rn(float2{a.x, a.y});
  o.h[1] = __float22bfloat162_rn(float2{a.z, a.w});
  o.h[2] = __float22bfloat162_rn(float2{b.x, b.y});
  o.h[3] = __float22bfloat162_rn(float2{b.z, b.w});
  return o.v;
}

// ---------------- K0: hidden fp32 -> bf16 ----------------
__global__ __launch_bounds__(256) void cvt_kernel(const float* __restrict__ x,
                                                  unsigned short* __restrict__ y) {
  int i = (blockIdx.x * 256 + threadIdx.x) * 8;
  float4 a = *(const float4*)(x + i);
  float4 b = *(const float4*)(x + i + 4);
  ushort4 o0 = { f2bf(a.x), f2bf(a.y), f2bf(a.z), f2bf(a.w) };
  ushort4 o1 = { f2bf(b.x), f2bf(b.y), f2bf(b.z), f2bf(b.w) };
  *(ushort4*)(y + i) = o0;
  *(ushort4*)(y + i + 4) = o1;
}

// ================= GEMM core: wave-autonomous FULL-M columns =================
// One wave per 32 output columns, covering ALL M=256 rows -> B rows are read by
// exactly ONE wave (B traffic = B size, no duplication; round-3's 16x overfetch
// fixed). A (bf16, small) is re-read per wave from L2 (260 MB aggregate ~ 19
// TB/s < 34.5 TB/s L2 ceiling). No LDS, no barriers: each wave free-runs with
// unroll-2 keeping ~8 KB of B in flight. 32 f32x4 accumulators (128 VGPR).
// MFMA 16x16x32 fragment mapping (numerically verified in prior rounds):
//   A-frag lane l: A[mt*16 + (l&15)][kk + 8*(l>>4) .. +8]
//   B-frag lane l: B[n + (l&15)][kk + 8*(l>>4) .. +8] (fp32 -> cvt_pk bf16)
//   C lane l reg r: C[mt*16 + (l>>4)*4 + r][n + (l&15)]

// ---------------- K1: GEMM1  P = hidden @ [Wqkv_half;Wgate;Walpha;Wbeta]^T ----------------
// 260 single-wave blocks; block b owns cols b*32..b*32+31, all 256 rows.
__global__ __launch_bounds__(64) void gemm1_kernel(
    const unsigned short* __restrict__ A16,   // [256][2048] bf16
    const float* __restrict__ Wqkv, const float* __restrict__ Wgate,
    const float* __restrict__ Walpha, const float* __restrict__ Wbeta,
    float* __restrict__ P) {                  // [256][8320] fp32
  const int lane = threadIdx.x & 63;
  const int l15 = lane & 15, hi8 = (lane >> 4) * 8;
  const int n0 = blockIdx.x * 32;

  const unsigned short* Abase = A16 + (size_t)l15 * K1 + hi8;
  const float* Brow0;
  const float* Brow1;
  {
    int ng0 = n0 + l15;
    int ng1 = n0 + 16 + l15;
    const float* b0;
    const float* b1;
    if (ng0 < 4096)       b0 = Wqkv  + (size_t)(4096 + ng0) * K1;
    else if (ng0 < 8192)  b0 = Wgate + (size_t)(ng0 - 4096) * K1;
    else if (ng0 < 8224)  b0 = Walpha + (size_t)(ng0 - 8192) * K1;
    else if (ng0 < 8256)  b0 = Wbeta + (size_t)(ng0 - 8224) * K1;
    else                  b0 = Walpha + (size_t)l15 * K1;          // pad, discarded
    if (ng1 < 4096)       b1 = Wqkv  + (size_t)(4096 + ng1) * K1;
    else if (ng1 < 8192)  b1 = Wgate + (size_t)(ng1 - 4096) * K1;
    else if (ng1 < 8224)  b1 = Walpha + (size_t)(ng1 - 8192) * K1;
    else if (ng1 < 8256)  b1 = Wbeta + (size_t)(ng1 - 8224) * K1;
    else                  b1 = Walpha + (size_t)l15 * K1;          // pad
    Brow0 = b0 + hi8;
    Brow1 = b1 + hi8;
  }

  f32x4 acc0[16], acc1[16];
#pragma unroll
  for (int i = 0; i < 16; i++) {
    f32x4 z = {0.f, 0.f, 0.f, 0.f};
    acc0[i] = z; acc1[i] = z;
  }

#pragma unroll 2
  for (int kk = 0; kk < K1; kk += 32) {
    float4 b0a = *(const float4*)(Brow0 + kk);
    float4 b0b = *(const float4*)(Brow0 + kk + 4);
    float4 b1a = *(const float4*)(Brow1 + kk);
    float4 b1b = *(const float4*)(Brow1 + kk + 4);
    bf16x8 bF0 = pack8(b0a, b0b);
    bf16x8 bF1 = pack8(b1a, b1b);
#pragma unroll
    for (int i = 0; i < 16; i++) {
      bf16x8 aF = *(const bf16x8*)(Abase + (size_t)i * 16 * K1 + kk);
      acc0[i] = __builtin_amdgcn_mfma_f32_16x16x32_bf16(aF, bF0, acc0[i], 0, 0, 0);
      acc1[i] = __builtin_amdgcn_mfma_f32_16x16x32_bf16(aF, bF1, acc1[i], 0, 0, 0);
    }
  }

  const int r0 = (lane >> 4) * 4;
#pragma unroll
  for (int i = 0; i < 16; i++) {
    int row = i * 16 + r0;
#pragma unroll
    for (int r = 0; r < 4; r++) {
      P[(size_t)(row + r) * N1 + (n0 + l15)] = acc0[i][r];
      P[(size_t)(row + r) * N1 + (n0 + 16 + l15)] = acc1[i][r];
    }
  }
}

// ---------------- K2: per-row fused conv + SSM + RMS + gate; writes core bf16 ----------------
__global__ __launch_bounds__(512) void fuse_kernel(
    const float* __restrict__ P,        // [256][8320]
    const float* __restrict__ bqkv,     // [8192]
    const float* __restrict__ ck,       // [8192][4]
    const float* __restrict__ cstate,   // [256][4][8192]
    const float* __restrict__ ssa,      // [32]
    const float* __restrict__ dtb,      // [32]
    const float* __restrict__ nw,       // [128]
    const float* __restrict__ sstate,   // [256][32]
    unsigned short* __restrict__ C16) { // [256][4096] bf16
  __shared__ __align__(16) float cb[4096];
  __shared__ float gsum[64];
  __shared__ float ssl[32];
  __shared__ float red[16];
  const int b = blockIdx.x, tid = threadIdx.x;
  const int lane = tid & 63, wv = tid >> 6;
  const float* P0 = P + (size_t)b * N1;

  if (wv == 0) {   // mean(ssm_norm_weight)
    float m = nw[lane] + nw[lane + 64];
#pragma unroll
    for (int off = 32; off; off >>= 1) m += __shfl_down(m, off, 64);
    if (lane == 0) red[8] = m * (1.f / 128.f);
  }

  // pass 1: core_base (conv) + group sums via 16-lane shuffle reduce
#pragma unroll
  for (int it = 0; it < 2; it++) {
    int j = (it * 512 + tid) * 4;
    float4 q0 = *(const float4*)(P0 + j);
    float4 bq = *(const float4*)(bqkv + NQ + j);
    float mqx = q0.x + bq.x, mqy = q0.y + bq.y;
    float mqz = q0.z + bq.z, mqw = q0.w + bq.w;
    const float* csb = cstate + (size_t)b * 4 * 8192 + NQ + j;
    float4 c1 = *(const float4*)(csb + 8192);
    float4 c2 = *(const float4*)(csb + 16384);
    float4 c3 = *(const float4*)(csb + 24576);
    float4 k0v = *(const float4*)(ck + (size_t)(NQ + j) * 4);
    float4 k1v = *(const float4*)(ck + (size_t)(NQ + j + 1) * 4);
    float4 k2v = *(const float4*)(ck + (size_t)(NQ + j + 2) * 4);
    float4 k3v = *(const float4*)(ck + (size_t)(NQ + j + 3) * 4);
    float4 cbv;
    cbv.x = c1.x * k0v.x + c2.x * k0v.y + c3.x * k0v.z + mqx * k0v.w;
    cbv.y = c1.y * k1v.x + c2.y * k1v.y + c3.y * k1v.z + mqy * k1v.w;
    cbv.z = c1.z * k2v.x + c2.z * k2v.y + c3.z * k2v.z + mqz * k2v.w;
    cbv.w = c1.w * k3v.x + c2.w * k3v.y + c3.w * k3v.z + mqw * k3v.w;
    *(float4*)(cb + j) = cbv;
    float s = cbv.x + cbv.y + cbv.z + cbv.w;
    s += __shfl_xor(s, 1, 64); s += __shfl_xor(s, 2, 64);
    s += __shfl_xor(s, 4, 64); s += __shfl_xor(s, 8, 64);
    if ((lane & 15) == 0) gsum[(it * 512 + tid) >> 4] = s;
  }
  __syncthreads();

  if (tid < 32) {
    float a  = P0[8192 + tid];
    float bc = P0[8224 + tid];
    float kg = gsum[tid] * (1.f / 64.f);
    float vg = gsum[32 + tid] * (1.f / 64.f);
    float x = a + dtb[tid];
    float sp = fmaxf(x, 0.f) + log1pf(expf(-fabsf(x)));   // stable softplus
    float g = -expf(ssa[tid]) * sp;
    float beta = 1.f / (1.f + expf(-bc));
    float ns = expf(g) * sstate[b * 32 + tid] + beta * vg;
    ssl[tid] = ns / (1.f + expf(-kg));
  }
  __syncthreads();

  // pass 2: core1 = core_base + expanded; sum of squares
  float sq = 0.f;
  float4 c1r[2];
#pragma unroll
  for (int it = 0; it < 2; it++) {
    int j = (it * 512 + tid) * 4;
    float4 v = *(const float4*)(cb + j);
    float sv = ssl[j >> 7];
    v.x += sv; v.y += sv; v.z += sv; v.w += sv;
    c1r[it] = v;
    sq += v.x * v.x + v.y * v.y + v.z * v.z + v.w * v.w;
  }
#pragma unroll
  for (int off = 32; off; off >>= 1) sq += __shfl_down(sq, off, 64);
  if (lane == 0) red[wv] = sq;
  __syncthreads();
  if (tid == 0) {
    float t = red[0] + red[1] + red[2] + red[3] + red[4] + red[5] + red[6] + red[7];
    red[9] = rsqrtf(t * (1.f / 4096.f) + 1e-6f);
  }
  __syncthreads();
  float rms = red[9], mwv = red[8];

  // pass 3: apply gate, write bf16
#pragma unroll
  for (int it = 0; it < 2; it++) {
    int j = (it * 512 + tid) * 4;
    float4 g0x = *(const float4*)(P0 + NQ + j);
    float4 v = c1r[it];
    float ox = v.x * rms * mwv / (1.f + expf(-g0x.x));
    float oy = v.y * rms * mwv / (1.f + expf(-g0x.y));
    float oz = v.z * rms * mwv / (1.f + expf(-g0x.z));
    float ow = v.w * rms * mwv / (1.f + expf(-g0x.w));
    ushort4 u = { f2bf(ox), f2bf(oy), f2bf(oz), f2bf(ow) };
    *(ushort4*)(C16 + (size_t)b * 4096 + j) = u;
  }
}

// ---------------- K3: GEMM3 OP[z] = core @ Wout^T (full-M waves, split-K=4) ----------------
// 256 single-wave blocks: block = (z 0..3) x (nidx 0..63). Each wave owns cols
// nidx*32..+31, K-chunk z*1024..+1024, all 256 rows. B (Wout) read exactly once.
__global__ __launch_bounds__(64) void gemm3_kernel(
    const unsigned short* __restrict__ A16,  // core [256][4096] bf16
    const float* __restrict__ Wout,          // [2048][4096] fp32
    float* __restrict__ OP) {                // [4][256][2048] fp32 slabs
  const int lane = threadIdx.x & 63;
  const int l15 = lane & 15, hi8 = (lane >> 4) * 8;
  const int z = blockIdx.x >> 6;
  const int n0 = (blockIdx.x & 63) * 32;
  const int kb = z * 1024;

  const unsigned short* Abase = A16 + (size_t)l15 * K3 + kb + hi8;
  const float* Brow0 = Wout + (size_t)(n0 + l15) * K3 + kb + hi8;
  const float* Brow1 = Wout + (size_t)(n0 + 16 + l15) * K3 + kb + hi8;

  f32x4 acc0[16], acc1[16];
#pragma unroll
  for (int i = 0; i < 16; i++) {
    f32x4 zz = {0.f, 0.f, 0.f, 0.f};
    acc0[i] = zz; acc1[i] = zz;
  }

#pragma unroll 2
  for (int kk = 0; kk < 1024; kk += 32) {
    float4 b0a = *(const float4*)(Brow0 + kk);
    float4 b0b = *(const float4*)(Brow0 + kk + 4);
    float4 b1a = *(const float4*)(Brow1 + kk);
    float4 b1b = *(const float4*)(Brow1 + kk + 4);
    bf16x8 bF0 = pack8(b0a, b0b);
    bf16x8 bF1 = pack8(b1a, b1b);
#pragma unroll
    for (int i = 0; i < 16; i++) {
      bf16x8 aF = *(const bf16x8*)(Abase + (size_t)i * 16 * K3 + kk);
      acc0[i] = __builtin_amdgcn_mfma_f32_16x16x32_bf16(aF, bF0, acc0[i], 0, 0, 0);
      acc1[i] = __builtin_amdgcn_mfma_f32_16x16x32_bf16(aF, bF1, acc1[i], 0, 0, 0);
    }
  }

  float* Oz = OP + (size_t)z * ((size_t)BSZ * N3);
  const int r0 = (lane >> 4) * 4;
#pragma unroll
  for (int i = 0; i < 16; i++) {
    int row = i * 16 + r0;
#pragma unroll
    for (int r = 0; r < 4; r++) {
      Oz[(size_t)(row + r) * N3 + (n0 + l15)] = acc0[i][r];
      Oz[(size_t)(row + r) * N3 + (n0 + 16 + l15)] = acc1[i][r];
    }
  }
}

// ---------------- K4: reduce 4 slabs -> out ----------------
__global__ __launch_bounds__(256) void reduce_kernel(const float* __restrict__ OP,
                                                     float* __restrict__ out) {
  int i = (blockIdx.x * 256 + threadIdx.x) * 4;
  float4 s = *(const float4*)(OP + i);
#pragma unroll
  for (int z = 1; z < Z3; z++) {
    float4 v = *(const float4*)(OP + (size_t)z * BSZ * N3 + i);
    s.x += v.x; s.y += v.y; s.z += v.z; s.w += v.w;
  }
  *(float4*)(out + i) = s;
}

extern "C" void kernel_launch(void* const* d_in, const int* in_sizes, int n_in,
                              void* d_out, int out_size, void* d_ws, size_t ws_size,
                              hipStream_t stream) {
  const float* hidden = (const float*)d_in[0];
  const float* Wqkv   = (const float*)d_in[1];
  const float* bqkv   = (const float*)d_in[2];
  const float* Wgate  = (const float*)d_in[3];
  const float* Walpha = (const float*)d_in[4];
  const float* Wbeta  = (const float*)d_in[5];
  const float* Wout   = (const float*)d_in[6];
  const float* ssa    = (const float*)d_in[7];
  const float* dtb    = (const float*)d_in[8];
  const float* nw     = (const float*)d_in[9];
  const float* ck     = (const float*)d_in[10];
  const float* sstate = (const float*)d_in[11];
  const float* cstate = (const float*)d_in[12];
  float* out = (float*)d_out;

  char* ws = (char*)d_ws;
  unsigned short* A16 = (unsigned short*)ws;                          // 1 MB
  float* P   = (float*)(ws + (1 << 20));                              // 256*8320*4 = 8,519,680 B
  unsigned short* C16 = (unsigned short*)(ws + (1 << 20) + 8519680);  // 2 MB
  float* OP  = (float*)(ws + (1 << 20) + 8519680 + (2 << 20));        // 4*256*2048*4 = 8 MB

  cvt_kernel<<<256, 256, 0, stream>>>(hidden, A16);
  gemm1_kernel<<<260, 64, 0, stream>>>(A16, Wqkv, Wgate, Walpha, Wbeta, P);
  fuse_kernel<<<256, 512, 0, stream>>>(P, bqkv, ck, cstate, ssa, dtb, nw, sstate, C16);
  gemm3_kernel<<<256, 64, 0, stream>>>(C16, Wout, OP);
  reduce_kernel<<<512, 256, 0, stream>>>(OP, out);
}

// Round 5
// 281.047 us; speedup vs baseline: 1.4903x; 1.2668x over previous
//
#include <hip/hip_runtime.h>
#include <hip/hip_bf16.h>
#include <stdint.h>

// Problem constants
#define BSZ 256
#define NQ 4096          // Q_SIZE
#define N1 8320          // GEMM1 padded N: [qkv_half 4096 | gate 4096 | alpha 32 | beta 32 | pad 64]
#define K1 2048
#define N3 2048
#define K3 4096
#define Z3 4             // gemm3 split-K slabs

typedef __attribute__((ext_vector_type(8))) short bf16x8;
typedef __attribute__((ext_vector_type(4))) float f32x4;

__device__ __forceinline__ unsigned short f2bf(float f) {
  union { float f; unsigned u; } v; v.f = f;
  unsigned r = v.u + 0x7fffu + ((v.u >> 16) & 1u);   // RNE
  return (unsigned short)(r >> 16);
}

// fp32x8 -> bf16x8 via v_cvt_pk_bf16_f32 (RNE, same numerics as f2bf)
__device__ __forceinline__ bf16x8 pack8(float4 a, float4 b) {
  union { bf16x8 v; __hip_bfloat162 h[4]; } o;
  o.h[0] = __float22bfloat162_rn(float2{a.x, a.y});
  o.h[1] = __float22bfloat162_rn(float2{a.z, a.w});
  o.h[2] = __float22bfloat162_rn(float2{b.x, b.y});
  o.h[3] = __float22bfloat162_rn(float2{b.z, b.w});
  return o.v;
}

// ---------------- K0: hidden fp32 -> bf16 ----------------
__global__ __launch_bounds__(256) void cvt_kernel(const float* __restrict__ x,
                                                  unsigned short* __restrict__ y) {
  int i = (blockIdx.x * 256 + threadIdx.x) * 8;
  float4 a = *(const float4*)(x + i);
  float4 b = *(const float4*)(x + i + 4);
  ushort4 o0 = { f2bf(a.x), f2bf(a.y), f2bf(a.z), f2bf(a.w) };
  ushort4 o1 = { f2bf(b.x), f2bf(b.y), f2bf(b.z), f2bf(b.w) };
  *(ushort4*)(y + i) = o0;
  *(ushort4*)(y + i + 4) = o1;
}

// ================= GEMM core: full-M col-group blocks, in-block split-K ========
// Block owns 32 output columns x all M=256 rows -> B rows are read by exactly
// one block (no B duplication). 8 waves split K (round-4's 1-wave/block had
// 2.8% occupancy; this gives 2 waves/SIMD + 8x shorter per-wave dep chain).
// Partial accumulators combined by a 3-phase LDS tree (4 padded buffers).
// MFMA 16x16x32 fragment mapping (numerically verified in prior rounds):
//   A-frag lane l: A[mt*16 + (l&15)][kk + 8*(l>>4) .. +8]
//   B-frag lane l: B[n + (l&15)][kk + 8*(l>>4) .. +8] (fp32 -> cvt_pk bf16)
//   C lane l reg r: C[mt*16 + (l>>4)*4 + r][n + (l&15)]

#define LBUF (256 * 33)   // padded rows: bank = (row + col) % 32 -> conflict-light

__device__ __forceinline__ void reduce_store(const f32x4* acc0, const f32x4* acc1,
                                             float* lds, int lane, int wv,
                                             float* outp, int ostride, int n0) {
  const int l15 = lane & 15;
  const int r0 = (lane >> 4) * 4;
  // phase 1: waves 0-3 deposit into buffers 0-3
  if (wv < 4) {
    float* buf = lds + wv * LBUF;
#pragma unroll
    for (int i = 0; i < 16; i++)
#pragma unroll
      for (int r = 0; r < 4; r++) {
        int row = i * 16 + r0 + r;
        buf[row * 33 + l15] = acc0[i][r];
        buf[row * 33 + 16 + l15] = acc1[i][r];
      }
  }
  __syncthreads();
  // phase 2: waves 4-7 add into buffers 0-3
  if (wv >= 4) {
    float* buf = lds + (wv - 4) * LBUF;
#pragma unroll
    for (int i = 0; i < 16; i++)
#pragma unroll
      for (int r = 0; r < 4; r++) {
        int row = i * 16 + r0 + r;
        buf[row * 33 + l15] += acc0[i][r];
        buf[row * 33 + 16 + l15] += acc1[i][r];
      }
  }
  __syncthreads();
  // phase 3: buf0 += buf2, buf1 += buf3 (all 8 waves, row-partitioned)
  {
    float* d = lds + (wv >> 2) * LBUF;
    const float* s = lds + ((wv >> 2) + 2) * LBUF;
    int rbase = (wv & 3) * 64;
    int col = lane & 31;
#pragma unroll
    for (int j = 0; j < 32; j++) {
      int row = rbase + j * 2 + (lane >> 5);
      d[row * 33 + col] += s[row * 33 + col];
    }
  }
  __syncthreads();
  // phase 4: out = buf0 + buf1 (all 8 waves, 32 rows each)
  {
    int col = lane & 31;
    const float* b0 = lds;
    const float* b1 = lds + LBUF;
#pragma unroll
    for (int j = 0; j < 16; j++) {
      int row = wv * 32 + j * 2 + (lane >> 5);
      outp[(size_t)row * ostride + n0 + col] = b0[row * 33 + col] + b1[row * 33 + col];
    }
  }
}

// ---------------- K1: GEMM1  P = hidden @ [Wqkv_half;Wgate;Walpha;Wbeta]^T ----------------
// 260 blocks x 512 thr; block b owns cols b*32..+31; wave w owns K [w*256,+256)
__global__ __launch_bounds__(512, 2) void gemm1_kernel(
    const unsigned short* __restrict__ A16,   // [256][2048] bf16
    const float* __restrict__ Wqkv, const float* __restrict__ Wgate,
    const float* __restrict__ Walpha, const float* __restrict__ Wbeta,
    float* __restrict__ P) {                  // [256][8320] fp32
  __shared__ float lds[4 * LBUF];             // 135,168 B
  const int tid = threadIdx.x, lane = tid & 63, wv = tid >> 6;
  const int l15 = lane & 15, hi8 = (lane >> 4) * 8;
  const int n0 = blockIdx.x * 32;
  const int k0 = wv * 256;

  const unsigned short* Abase = A16 + (size_t)l15 * K1 + hi8;
  const float* Brow0;
  const float* Brow1;
  {
    int ng0 = n0 + l15;
    int ng1 = n0 + 16 + l15;
    const float* b0;
    const float* b1;
    if (ng0 < 4096)       b0 = Wqkv  + (size_t)(4096 + ng0) * K1;
    else if (ng0 < 8192)  b0 = Wgate + (size_t)(ng0 - 4096) * K1;
    else if (ng0 < 8224)  b0 = Walpha + (size_t)(ng0 - 8192) * K1;
    else if (ng0 < 8256)  b0 = Wbeta + (size_t)(ng0 - 8224) * K1;
    else                  b0 = Walpha + (size_t)l15 * K1;          // pad, discarded
    if (ng1 < 4096)       b1 = Wqkv  + (size_t)(4096 + ng1) * K1;
    else if (ng1 < 8192)  b1 = Wgate + (size_t)(ng1 - 4096) * K1;
    else if (ng1 < 8224)  b1 = Walpha + (size_t)(ng1 - 8192) * K1;
    else if (ng1 < 8256)  b1 = Wbeta + (size_t)(ng1 - 8224) * K1;
    else                  b1 = Walpha + (size_t)l15 * K1;          // pad
    Brow0 = b0 + hi8;
    Brow1 = b1 + hi8;
  }

  f32x4 acc0[16], acc1[16];
#pragma unroll
  for (int i = 0; i < 16; i++) {
    f32x4 z = {0.f, 0.f, 0.f, 0.f};
    acc0[i] = z; acc1[i] = z;
  }

#pragma unroll 2
  for (int kk = k0; kk < k0 + 256; kk += 32) {
    float4 b0a = *(const float4*)(Brow0 + kk);
    float4 b0b = *(const float4*)(Brow0 + kk + 4);
    float4 b1a = *(const float4*)(Brow1 + kk);
    float4 b1b = *(const float4*)(Brow1 + kk + 4);
    bf16x8 bF0 = pack8(b0a, b0b);
    bf16x8 bF1 = pack8(b1a, b1b);
#pragma unroll
    for (int i = 0; i < 16; i++) {
      bf16x8 aF = *(const bf16x8*)(Abase + (size_t)i * 16 * K1 + kk);
      acc0[i] = __builtin_amdgcn_mfma_f32_16x16x32_bf16(aF, bF0, acc0[i], 0, 0, 0);
      acc1[i] = __builtin_amdgcn_mfma_f32_16x16x32_bf16(aF, bF1, acc1[i], 0, 0, 0);
    }
  }

  reduce_store(acc0, acc1, lds, lane, wv, P, N1, n0);
}

// ---------------- K2: per-row fused conv + SSM + RMS + gate; writes core bf16 ----------------
__global__ __launch_bounds__(512) void fuse_kernel(
    const float* __restrict__ P,        // [256][8320]
    const float* __restrict__ bqkv,     // [8192]
    const float* __restrict__ ck,       // [8192][4]
    const float* __restrict__ cstate,   // [256][4][8192]
    const float* __restrict__ ssa,      // [32]
    const float* __restrict__ dtb,      // [32]
    const float* __restrict__ nw,       // [128]
    const float* __restrict__ sstate,   // [256][32]
    unsigned short* __restrict__ C16) { // [256][4096] bf16
  __shared__ __align__(16) float cb[4096];
  __shared__ float gsum[64];
  __shared__ float ssl[32];
  __shared__ float red[16];
  const int b = blockIdx.x, tid = threadIdx.x;
  const int lane = tid & 63, wv = tid >> 6;
  const float* P0 = P + (size_t)b * N1;

  if (wv == 0) {   // mean(ssm_norm_weight)
    float m = nw[lane] + nw[lane + 64];
#pragma unroll
    for (int off = 32; off; off >>= 1) m += __shfl_down(m, off, 64);
    if (lane == 0) red[8] = m * (1.f / 128.f);
  }

  // pass 1: core_base (conv) + group sums via 16-lane shuffle reduce
#pragma unroll
  for (int it = 0; it < 2; it++) {
    int j = (it * 512 + tid) * 4;
    float4 q0 = *(const float4*)(P0 + j);
    float4 bq = *(const float4*)(bqkv + NQ + j);
    float mqx = q0.x + bq.x, mqy = q0.y + bq.y;
    float mqz = q0.z + bq.z, mqw = q0.w + bq.w;
    const float* csb = cstate + (size_t)b * 4 * 8192 + NQ + j;
    float4 c1 = *(const float4*)(csb + 8192);
    float4 c2 = *(const float4*)(csb + 16384);
    float4 c3 = *(const float4*)(csb + 24576);
    float4 k0v = *(const float4*)(ck + (size_t)(NQ + j) * 4);
    float4 k1v = *(const float4*)(ck + (size_t)(NQ + j + 1) * 4);
    float4 k2v = *(const float4*)(ck + (size_t)(NQ + j + 2) * 4);
    float4 k3v = *(const float4*)(ck + (size_t)(NQ + j + 3) * 4);
    float4 cbv;
    cbv.x = c1.x * k0v.x + c2.x * k0v.y + c3.x * k0v.z + mqx * k0v.w;
    cbv.y = c1.y * k1v.x + c2.y * k1v.y + c3.y * k1v.z + mqy * k1v.w;
    cbv.z = c1.z * k2v.x + c2.z * k2v.y + c3.z * k2v.z + mqz * k2v.w;
    cbv.w = c1.w * k3v.x + c2.w * k3v.y + c3.w * k3v.z + mqw * k3v.w;
    *(float4*)(cb + j) = cbv;
    float s = cbv.x + cbv.y + cbv.z + cbv.w;
    s += __shfl_xor(s, 1, 64); s += __shfl_xor(s, 2, 64);
    s += __shfl_xor(s, 4, 64); s += __shfl_xor(s, 8, 64);
    if ((lane & 15) == 0) gsum[(it * 512 + tid) >> 4] = s;
  }
  __syncthreads();

  if (tid < 32) {
    float a  = P0[8192 + tid];
    float bc = P0[8224 + tid];
    float kg = gsum[tid] * (1.f / 64.f);
    float vg = gsum[32 + tid] * (1.f / 64.f);
    float x = a + dtb[tid];
    float sp = fmaxf(x, 0.f) + log1pf(expf(-fabsf(x)));   // stable softplus
    float g = -expf(ssa[tid]) * sp;
    float beta = 1.f / (1.f + expf(-bc));
    float ns = expf(g) * sstate[b * 32 + tid] + beta * vg;
    ssl[tid] = ns / (1.f + expf(-kg));
  }
  __syncthreads();

  // pass 2: core1 = core_base + expanded; sum of squares
  float sq = 0.f;
  float4 c1r[2];
#pragma unroll
  for (int it = 0; it < 2; it++) {
    int j = (it * 512 + tid) * 4;
    float4 v = *(const float4*)(cb + j);
    float sv = ssl[j >> 7];
    v.x += sv; v.y += sv; v.z += sv; v.w += sv;
    c1r[it] = v;
    sq += v.x * v.x + v.y * v.y + v.z * v.z + v.w * v.w;
  }
#pragma unroll
  for (int off = 32; off; off >>= 1) sq += __shfl_down(sq, off, 64);
  if (lane == 0) red[wv] = sq;
  __syncthreads();
  if (tid == 0) {
    float t = red[0] + red[1] + red[2] + red[3] + red[4] + red[5] + red[6] + red[7];
    red[9] = rsqrtf(t * (1.f / 4096.f) + 1e-6f);
  }
  __syncthreads();
  float rms = red[9], mwv = red[8];

  // pass 3: apply gate, write bf16
#pragma unroll
  for (int it = 0; it < 2; it++) {
    int j = (it * 512 + tid) * 4;
    float4 g0x = *(const float4*)(P0 + NQ + j);
    float4 v = c1r[it];
    float ox = v.x * rms * mwv / (1.f + expf(-g0x.x));
    float oy = v.y * rms * mwv / (1.f + expf(-g0x.y));
    float oz = v.z * rms * mwv / (1.f + expf(-g0x.z));
    float ow = v.w * rms * mwv / (1.f + expf(-g0x.w));
    ushort4 u = { f2bf(ox), f2bf(oy), f2bf(oz), f2bf(ow) };
    *(ushort4*)(C16 + (size_t)b * 4096 + j) = u;
  }
}

// ---------------- K3: GEMM3 OP[z] = core @ Wout^T ----------------
// grid (64, 4) x 512 thr: block (n,z) owns cols n*32..+31, K-slab z*1024..+1024;
// wave w takes K-chunk of 128 (4 steps). LDS tree-reduce, write OP slab z.
__global__ __launch_bounds__(512, 2) void gemm3_kernel(
    const unsigned short* __restrict__ A16,  // core [256][4096] bf16
    const float* __restrict__ Wout,          // [2048][4096] fp32
    float* __restrict__ OP) {                // [4][256][2048] fp32 slabs
  __shared__ float lds[4 * LBUF];
  const int tid = threadIdx.x, lane = tid & 63, wv = tid >> 6;
  const int l15 = lane & 15, hi8 = (lane >> 4) * 8;
  const int n0 = blockIdx.x * 32;
  const int z = blockIdx.y;
  const int k0 = z * 1024 + wv * 128;

  const unsigned short* Abase = A16 + (size_t)l15 * K3 + hi8;
  const float* Brow0 = Wout + (size_t)(n0 + l15) * K3 + hi8;
  const float* Brow1 = Wout + (size_t)(n0 + 16 + l15) * K3 + hi8;

  f32x4 acc0[16], acc1[16];
#pragma unroll
  for (int i = 0; i < 16; i++) {
    f32x4 zz = {0.f, 0.f, 0.f, 0.f};
    acc0[i] = zz; acc1[i] = zz;
  }

#pragma unroll 2
  for (int kk = k0; kk < k0 + 128; kk += 32) {
    float4 b0a = *(const float4*)(Brow0 + kk);
    float4 b0b = *(const float4*)(Brow0 + kk + 4);
    float4 b1a = *(const float4*)(Brow1 + kk);
    float4 b1b = *(const float4*)(Brow1 + kk + 4);
    bf16x8 bF0 = pack8(b0a, b0b);
    bf16x8 bF1 = pack8(b1a, b1b);
#pragma unroll
    for (int i = 0; i < 16; i++) {
      bf16x8 aF = *(const bf16x8*)(Abase + (size_t)i * 16 * K3 + kk);
      acc0[i] = __builtin_amdgcn_mfma_f32_16x16x32_bf16(aF, bF0, acc0[i], 0, 0, 0);
      acc1[i] = __builtin_amdgcn_mfma_f32_16x16x32_bf16(aF, bF1, acc1[i], 0, 0, 0);
    }
  }

  reduce_store(acc0, acc1, lds, lane, wv, OP + (size_t)z * BSZ * N3, N3, n0);
}

// ---------------- K4: reduce 4 slabs -> out ----------------
__global__ __launch_bounds__(256) void reduce_kernel(const float* __restrict__ OP,
                                                     float* __restrict__ out) {
  int i = (blockIdx.x * 256 + threadIdx.x) * 4;
  float4 s = *(const float4*)(OP + i);
#pragma unroll
  for (int z = 1; z < Z3; z++) {
    float4 v = *(const float4*)(OP + (size_t)z * BSZ * N3 + i);
    s.x += v.x; s.y += v.y; s.z += v.z; s.w += v.w;
  }
  *(float4*)(out + i) = s;
}

extern "C" void kernel_launch(void* const* d_in, const int* in_sizes, int n_in,
                              void* d_out, int out_size, void* d_ws, size_t ws_size,
                              hipStream_t stream) {
  const float* hidden = (const float*)d_in[0];
  const float* Wqkv   = (const float*)d_in[1];
  const float* bqkv   = (const float*)d_in[2];
  const float* Wgate  = (const float*)d_in[3];
  const float* Walpha = (const float*)d_in[4];
  const float* Wbeta  = (const float*)d_in[5];
  const float* Wout   = (const float*)d_in[6];
  const float* ssa    = (const float*)d_in[7];
  const float* dtb    = (const float*)d_in[8];
  const float* nw     = (const float*)d_in[9];
  const float* ck     = (const float*)d_in[10];
  const float* sstate = (const float*)d_in[11];
  const float* cstate = (const float*)d_in[12];
  float* out = (float*)d_out;

  char* ws = (char*)d_ws;
  unsigned short* A16 = (unsigned short*)ws;                          // 1 MB
  float* P   = (float*)(ws + (1 << 20));                              // 256*8320*4 = 8,519,680 B
  unsigned short* C16 = (unsigned short*)(ws + (1 << 20) + 8519680);  // 2 MB
  float* OP  = (float*)(ws + (1 << 20) + 8519680 + (2 << 20));        // 4*256*2048*4 = 8 MB

  cvt_kernel<<<256, 256, 0, stream>>>(hidden, A16);
  gemm1_kernel<<<260, 512, 0, stream>>>(A16, Wqkv, Wgate, Walpha, Wbeta, P);
  fuse_kernel<<<256, 512, 0, stream>>>(P, bqkv, ck, cstate, ssa, dtb, nw, sstate, C16);
  gemm3_kernel<<<dim3(64, 4), 512, 0, stream>>>(C16, Wout, OP);
  reduce_kernel<<<512, 256, 0, stream>>>(OP, out);
}